// Round 2
// baseline (20898.108 us; speedup 1.0000x reference)
//
#include <hip/hip_runtime.h>
#include <hip/hip_bf16.h>

typedef __bf16 bf16x8 __attribute__((ext_vector_type(8)));
typedef float f32x4 __attribute__((ext_vector_type(4)));

#define BB   128
#define SS   512
#define DD   128
#define HH   1024
#define OO   64
#define IIN  257

// scan decomposition: 2 batch groups x 128 blocks; each block owns 8 h-cols (32 gate cols)
#define NGROUP 2
#define GBLK   128
#define MG     64     // batch rows per group
#define NC     32     // gate cols per block
#define KK_H   32     // 1024/32
#define KK_X   9      // 288/32 (257 padded to 288, ti folded in at k=256)

#define XTP_SLAB  18432    // 4mt * 9kk * 64lane * 8 bf16 per (t,p)
#define HBUF_SLAB 65536    // 4mt * 32kk * 64lane * 8 bf16 per (p,buf)

// ws layout (bytes): [0,1024) flags (256 u32) | [1024, 1024+512K) hbuf (4 slabs)
// | hlast fp32 128x1024 | xtp bf16 1024 slabs
#define WS_HBUF  1024
#define WS_HLAST 525312
#define WS_XTP   1049600

__global__ void prepack_kernel(const float* __restrict__ x, const float* __restrict__ mask,
                               const float* __restrict__ ti, __bf16* __restrict__ xtp) {
  int idx = blockIdx.x * 256 + threadIdx.x;        // 1024 slabs * 18432
  int slab = idx / XTP_SLAB;
  int rem  = idx - slab * XTP_SLAB;
  int p = slab & 1, t = slab >> 1;
  int j = rem & 7, l = (rem >> 3) & 63;
  int t2 = rem >> 9;                               // 0..35
  int kk = t2 % 9, mt = t2 / 9;
  int b = p * MG + mt * 16 + (l & 15);
  int k = kk * 32 + ((l >> 4) << 3) + j;
  float v;
  if (k < 128)       v = x[(b * SS + t) * DD + k];
  else if (k < 256)  v = mask[(b * SS + t) * DD + (k - 128)];
  else if (k == 256) v = ti[b * SS + t];
  else               v = 0.f;
  xtp[idx] = (__bf16)v;
}

__device__ __forceinline__ float sigmoid_f(float v) { return 1.f / (1.f + __expf(-v)); }
__device__ __forceinline__ float tanh_f(float v)    { return 1.f - 2.f / (__expf(2.f * v) + 1.f); }

__launch_bounds__(256, 1)
__global__ void lstm_scan(const float* __restrict__ W_ih, const float* __restrict__ W_hh,
                          const float* __restrict__ b_ih, const float* __restrict__ b_hh,
                          const __bf16* __restrict__ xtp, __bf16* __restrict__ hbuf,
                          float* __restrict__ hlast, unsigned int* __restrict__ flags) {
  // fragment-packed weights, resident for all 512 steps
  __shared__ __bf16 whh_lds[2 * KK_H * 512];   // 64 KB : [nt][kk][lane][j]
  __shared__ __bf16 wih_lds[2 * KK_X * 512];   // 18 KB
  __shared__ float  bias_lds[NC];
  __shared__ float  gstage[64 * 36];           // 9 KB, padded stride 36
  __shared__ float  c_lds[512];                // cell state [m][j]

  const int tid = threadIdx.x;
  const int bid = blockIdx.x;
  // XCD swizzle: round-robin bid%8 = XCD. Group 0 -> XCDs 0-3, group 1 -> XCDs 4-7.
  const int r8  = bid & 7;
  const int p   = r8 >> 2;                 // batch group
  const int bIG = (bid >> 3) * 4 + (r8 & 3);   // [0,128) within group
  const int j0  = bIG * 8;                 // owned h-columns [j0, j0+8)

  // ---- one-time init: pack W_hh / W_ih slices into LDS in B-fragment order ----
  for (int e = tid; e < 2 * KK_H * 512; e += 256) {
    int j = e & 7, l = (e >> 3) & 63, kk = (e >> 9) & 31, nt = e >> 14;
    int n = nt * 16 + (l & 15);                       // n = gate*8 + jj
    int col = ((n >> 3) << 10) + j0 + (n & 7);        // gate*1024 + j0 + jj
    int k = kk * 32 + ((l >> 4) << 3) + j;
    whh_lds[e] = (__bf16)W_hh[col * HH + k];
  }
  for (int e = tid; e < 2 * KK_X * 512; e += 256) {
    int j = e & 7, l = (e >> 3) & 63;
    int t2 = e >> 9;                                  // 0..17
    int kk = t2 % 9, nt = t2 / 9;
    int n = nt * 16 + (l & 15);
    int col = ((n >> 3) << 10) + j0 + (n & 7);
    int k = kk * 32 + ((l >> 4) << 3) + j;
    wih_lds[e] = (k < IIN) ? (__bf16)W_ih[col * IIN + k] : (__bf16)0.f;
  }
  if (tid < NC) {
    int n = tid;
    int col = ((n >> 3) << 10) + j0 + (n & 7);
    bias_lds[n] = b_ih[col] + b_hh[col];
  }
  for (int e = tid; e < 512; e += 256) c_lds[e] = 0.f;
  __syncthreads();

  const int w = tid >> 6;    // wave id = M-tile
  const int l = tid & 63;
  unsigned int* gflags = flags + p * 128;

  for (int t = 0; t < SS; ++t) {
    const int rb = t & 1, wb = rb ^ 1;
    const __bf16* hb  = hbuf + (p * 2 + rb) * HBUF_SLAB + w * (KK_H * 512);
    const __bf16* xb  = xtp + (size_t)(t * 2 + p) * XTP_SLAB + w * (KK_X * 512);
    f32x4 acc0 = {0.f, 0.f, 0.f, 0.f};
    f32x4 acc1 = {0.f, 0.f, 0.f, 0.f};

    // x-part: K = 288, independent of h_t -> runs BEFORE the barrier poll,
    // hiding it under straggler wait.
    #pragma unroll
    for (int kk = 0; kk < KK_X; ++kk) {
      bf16x8 a  = *(const bf16x8*)(xb + kk * 512 + l * 8);
      bf16x8 b0 = *(const bf16x8*)(wih_lds + kk * 512 + l * 8);
      bf16x8 b1 = *(const bf16x8*)(wih_lds + KK_X * 512 + kk * 512 + l * 8);
      acc0 = __builtin_amdgcn_mfma_f32_16x16x32_bf16(a, b0, acc0, 0, 0, 0);
      acc1 = __builtin_amdgcn_mfma_f32_16x16x32_bf16(a, b1, acc1, 0, 0, 0);
    }

    // ---- barrier wait: all group blocks must have published h_t ----
    if (t > 0) {
      if (tid < 64) {
        const unsigned int tgt = (unsigned int)t;
        int it = 0;
        for (;;) {
          unsigned int fa = __hip_atomic_load(gflags + tid,      __ATOMIC_RELAXED, __HIP_MEMORY_SCOPE_AGENT);
          unsigned int fb = __hip_atomic_load(gflags + 64 + tid, __ATOMIC_RELAXED, __HIP_MEMORY_SCOPE_AGENT);
          if (!__ballot(fa < tgt || fb < tgt)) break;
          if (((++it) & 15) == 0) __threadfence();   // progress guarantee vs stale lines
          __builtin_amdgcn_s_sleep(1);
        }
      }
      __syncthreads();
      __threadfence();   // acquire: invalidate caches before reading remote h
    }

    // h-part: K = 1024, A streamed from global (fragment-packed), B from LDS
    #pragma unroll 8
    for (int kk = 0; kk < KK_H; ++kk) {
      bf16x8 a  = *(const bf16x8*)(hb + kk * 512 + l * 8);
      bf16x8 b0 = *(const bf16x8*)(whh_lds + kk * 512 + l * 8);
      bf16x8 b1 = *(const bf16x8*)(whh_lds + KK_H * 512 + kk * 512 + l * 8);
      acc0 = __builtin_amdgcn_mfma_f32_16x16x32_bf16(a, b0, acc0, 0, 0, 0);
      acc1 = __builtin_amdgcn_mfma_f32_16x16x32_bf16(a, b1, acc1, 0, 0, 0);
    }

    // stage accumulators (C-layout: col=lane&15, row=(lane>>4)*4+r) to LDS
    {
      int q = l >> 4, n = l & 15;
      float bi0 = bias_lds[n], bi1 = bias_lds[16 + n];
      #pragma unroll
      for (int rr = 0; rr < 4; ++rr) {
        int m = w * 16 + q * 4 + rr;
        gstage[m * 36 + n]      = acc0[rr] + bi0;
        gstage[m * 36 + 16 + n] = acc1[rr] + bi1;
      }
    }
    __syncthreads();

    // gate phase: 512 (m,j) pairs, 2 per thread
    __bf16* hw = hbuf + (p * 2 + wb) * HBUF_SLAB;
    #pragma unroll
    for (int e = tid; e < 512; e += 256) {
      int m = e >> 3, j = e & 7;
      float gi = gstage[m * 36 + j];
      float gf = gstage[m * 36 + 8 + j];
      float gg = gstage[m * 36 + 16 + j];
      float go = gstage[m * 36 + 24 + j];
      float i_ = sigmoid_f(gi);
      float f_ = sigmoid_f(gf);
      float g_ = tanh_f(gg);
      float o_ = sigmoid_f(go);
      float c  = f_ * c_lds[e] + i_ * g_;
      c_lds[e] = c;
      float h  = o_ * tanh_f(c);
      // write h into next-step A-fragment-packed buffer
      int k = j0 + j;
      int mt = m >> 4, nn = m & 15, kk2 = k >> 5, q2 = (k >> 3) & 3, jj = k & 7;
      hw[((mt * 32 + kk2) * 64 + q2 * 16 + nn) * 8 + jj] = (__bf16)h;
      if (t == SS - 1) hlast[(p * MG + m) * HH + k] = h;
    }

    // ---- signal: h_{t+1} published (release store to own flag, no RMW) ----
    __threadfence();     // flush h writes to coherence point
    __syncthreads();     // all waves' fences done
    if (t < SS - 1 && tid == 0) {
      __hip_atomic_store(gflags + bIG, (unsigned int)(t + 1),
                         __ATOMIC_RELEASE, __HIP_MEMORY_SCOPE_AGENT);
    }
  }
}

__global__ void fc_kernel(const float* __restrict__ hlast, const float* __restrict__ W_fc,
                          const float* __restrict__ b_fc, float* __restrict__ out) {
  int b = blockIdx.x;            // 128
  int t = threadIdx.x;           // 256
  int o = t >> 2, part = t & 3;
  const float* hr = hlast + b * HH;
  const float* wr = W_fc + o * HH;
  float s = 0.f;
  #pragma unroll 4
  for (int k0 = part * 4; k0 < HH; k0 += 16) {
    float4 hv = *(const float4*)(hr + k0);
    float4 wv = *(const float4*)(wr + k0);
    s += hv.x * wv.x + hv.y * wv.y + hv.z * wv.z + hv.w * wv.w;
  }
  s += __shfl_xor(s, 1);
  s += __shfl_xor(s, 2);
  if (part == 0) out[b * OO + o] = s + b_fc[o];
}

extern "C" void kernel_launch(void* const* d_in, const int* in_sizes, int n_in,
                              void* d_out, int out_size, void* d_ws, size_t ws_size,
                              hipStream_t stream) {
  const float* x    = (const float*)d_in[0];
  const float* mask = (const float*)d_in[1];
  const float* ti   = (const float*)d_in[2];
  const float* W_ih = (const float*)d_in[3];
  const float* W_hh = (const float*)d_in[4];
  const float* b_ih = (const float*)d_in[5];
  const float* b_hh = (const float*)d_in[6];
  const float* W_fc = (const float*)d_in[7];
  const float* b_fc = (const float*)d_in[8];
  float* out = (float*)d_out;

  char* ws = (char*)d_ws;
  unsigned int* flags = (unsigned int*)ws;
  __bf16* hbuf  = (__bf16*)(ws + WS_HBUF);
  float*  hlast = (float*)(ws + WS_HLAST);
  __bf16* xtp   = (__bf16*)(ws + WS_XTP);

  // zero flags + h double-buffers (ws is poisoned 0xAA before each launch)
  hipMemsetAsync(ws, 0, WS_HLAST, stream);

  prepack_kernel<<<(1024 * XTP_SLAB) / 256, 256, 0, stream>>>(x, mask, ti, xtp);
  lstm_scan<<<NGROUP * GBLK, 256, 0, stream>>>(W_ih, W_hh, b_ih, b_hh, xtp, hbuf, hlast, flags);
  fc_kernel<<<BB, 256, 0, stream>>>(hlast, W_fc, b_fc, out);
}

// Round 3
// 2421.877 us; speedup vs baseline: 8.6289x; 8.6289x over previous
//
#include <hip/hip_runtime.h>
#include <hip/hip_bf16.h>

typedef __bf16 bf16x8 __attribute__((ext_vector_type(8)));
typedef float f32x4 __attribute__((ext_vector_type(4)));
typedef unsigned int u32x4 __attribute__((ext_vector_type(4)));

#define BB   128
#define SS   512
#define DD   128
#define HH   1024
#define OO   64
#define IIN  257

// scan decomposition: 2 batch groups x 128 blocks; each block owns 8 h-cols (32 gate cols)
#define NGROUP 2
#define GBLK   128
#define MG     64     // batch rows per group
#define NC     32     // gate cols per block
#define KK_H   32     // 1024/32
#define KK_X   9      // 288/32 (257 padded to 288, ti folded in at k=256)

#define XTP_SLAB  18432    // 4mt * 9kk * 64lane * 8 bf16 per (t,p)
#define HBUF_SLAB 65536    // 4mt * 32kk * 64lane * 8 bf16 per (p,buf)

// ws layout (bytes): [0,1024) flags (256 u32) | [1024, 1024+512K) hbuf (4 slabs)
// | hlast fp32 128x1024 | xtp bf16 1024 slabs
#define WS_HBUF  1024
#define WS_HLAST 525312
#define WS_XTP   1049600

// ---- device-scope (agent, sc1) memory ops: bypass L1/L2, coherent at L3 (MALL).
// No buffer_wbl2 / buffer_inv needed anywhere -> no full-L2 flush serialization.
__device__ __forceinline__ u32x4 ldg_dev16(const void* p) {
  u32x4 r;
  asm volatile("global_load_dwordx4 %0, %1, off sc1" : "=v"(r) : "v"(p));
  return r;
}
__device__ __forceinline__ void stg_dev4(void* p, unsigned int v) {
  asm volatile("global_store_dword %0, %1, off sc1" :: "v"(p), "v"(v));
}
__device__ __forceinline__ bf16x8 asbf(u32x4 v) {
  union { u32x4 u; bf16x8 h; } c; c.u = v; return c.h;
}

// wait until <= CNT vmem ops outstanding, and make the 8 claimed vectors
// data-depend on the wait so MFMAs can't be scheduled above it.
#define CLAIMW(CNTSTR, A)                                            \
  asm volatile("s_waitcnt vmcnt(" CNTSTR ")"                         \
    : "+v"((A)[0]), "+v"((A)[1]), "+v"((A)[2]), "+v"((A)[3]),        \
      "+v"((A)[4]), "+v"((A)[5]), "+v"((A)[6]), "+v"((A)[7]))

__global__ void prepack_kernel(const float* __restrict__ x, const float* __restrict__ mask,
                               const float* __restrict__ ti, __bf16* __restrict__ xtp) {
  int idx = blockIdx.x * 256 + threadIdx.x;        // 1024 slabs * 18432
  int slab = idx / XTP_SLAB;
  int rem  = idx - slab * XTP_SLAB;
  int p = slab & 1, t = slab >> 1;
  int j = rem & 7, l = (rem >> 3) & 63;
  int t2 = rem >> 9;                               // 0..35
  int kk = t2 % 9, mt = t2 / 9;
  int b = p * MG + mt * 16 + (l & 15);
  int k = kk * 32 + ((l >> 4) << 3) + j;
  float v;
  if (k < 128)       v = x[(b * SS + t) * DD + k];
  else if (k < 256)  v = mask[(b * SS + t) * DD + (k - 128)];
  else if (k == 256) v = ti[b * SS + t];
  else               v = 0.f;
  xtp[idx] = (__bf16)v;
}

__device__ __forceinline__ float sigmoid_f(float v) { return 1.f / (1.f + __expf(-v)); }
__device__ __forceinline__ float tanh_f(float v)    { return 1.f - 2.f / (__expf(2.f * v) + 1.f); }

__launch_bounds__(256, 1)
__global__ void lstm_scan(const float* __restrict__ W_ih, const float* __restrict__ W_hh,
                          const float* __restrict__ b_ih, const float* __restrict__ b_hh,
                          const __bf16* __restrict__ xtp, __bf16* __restrict__ hbuf,
                          float* __restrict__ hlast, unsigned int* __restrict__ flags) {
  // fragment-packed weights, resident for all 512 steps
  __shared__ __bf16 whh_lds[2 * KK_H * 512];   // 64 KB : [nt][kk][lane][j]
  __shared__ __bf16 wih_lds[2 * KK_X * 512];   // 18 KB
  __shared__ float  bias_lds[NC];
  __shared__ float  gstage[64 * 36];           // 9 KB, padded stride 36
  __shared__ float  c_lds[512];                // cell state [m][j]

  const int tid = threadIdx.x;
  const int bid = blockIdx.x;
  // XCD swizzle: round-robin bid%8 = XCD. Group 0 -> XCDs 0-3, group 1 -> XCDs 4-7.
  const int r8  = bid & 7;
  const int p   = r8 >> 2;                     // batch group
  const int bIG = (bid >> 3) * 4 + (r8 & 3);   // [0,128) within group
  const int j0  = bIG * 8;                     // owned h-columns [j0, j0+8)

  // ---- one-time init: pack W_hh / W_ih slices into LDS in B-fragment order ----
  for (int e = tid; e < 2 * KK_H * 512; e += 256) {
    int j = e & 7, l = (e >> 3) & 63, kk = (e >> 9) & 31, nt = e >> 14;
    int n = nt * 16 + (l & 15);                       // n = gate*8 + jj
    int col = ((n >> 3) << 10) + j0 + (n & 7);        // gate*1024 + j0 + jj
    int k = kk * 32 + ((l >> 4) << 3) + j;
    whh_lds[e] = (__bf16)W_hh[col * HH + k];
  }
  for (int e = tid; e < 2 * KK_X * 512; e += 256) {
    int j = e & 7, l = (e >> 3) & 63;
    int t2 = e >> 9;                                  // 0..17
    int kk = t2 % 9, nt = t2 / 9;
    int n = nt * 16 + (l & 15);
    int col = ((n >> 3) << 10) + j0 + (n & 7);
    int k = kk * 32 + ((l >> 4) << 3) + j;
    wih_lds[e] = (k < IIN) ? (__bf16)W_ih[col * IIN + k] : (__bf16)0.f;
  }
  if (tid < NC) {
    int n = tid;
    int col = ((n >> 3) << 10) + j0 + (n & 7);
    bias_lds[n] = b_ih[col] + b_hh[col];
  }
  for (int e = tid; e < 512; e += 256) c_lds[e] = 0.f;
  __syncthreads();

  const int w = tid >> 6;    // wave id = M-tile
  const int l = tid & 63;
  unsigned int* gflags = flags + p * 128;

  for (int t = 0; t < SS; ++t) {
    const int rb = t & 1, wb = rb ^ 1;
    const __bf16* hb  = hbuf + (p * 2 + rb) * HBUF_SLAB + w * (KK_H * 512);
    const __bf16* xb  = xtp + (size_t)(t * 2 + p) * XTP_SLAB + w * (KK_X * 512);
    f32x4 acc0 = {0.f, 0.f, 0.f, 0.f};
    f32x4 acc1 = {0.f, 0.f, 0.f, 0.f};

    // x-part: K = 288, independent of h_t -> runs BEFORE the barrier poll,
    // hiding it under straggler wait. Normal cached loads (read-only data,
    // L2 never invalidated now).
    #pragma unroll
    for (int kk = 0; kk < KK_X; ++kk) {
      bf16x8 a  = *(const bf16x8*)(xb + kk * 512 + l * 8);
      bf16x8 b0 = *(const bf16x8*)(wih_lds + kk * 512 + l * 8);
      bf16x8 b1 = *(const bf16x8*)(wih_lds + KK_X * 512 + kk * 512 + l * 8);
      acc0 = __builtin_amdgcn_mfma_f32_16x16x32_bf16(a, b0, acc0, 0, 0, 0);
      acc1 = __builtin_amdgcn_mfma_f32_16x16x32_bf16(a, b1, acc1, 0, 0, 0);
    }

    // ---- barrier wait: all group blocks must have published h_t (sc1 polls,
    // no cache maintenance) ----
    if (t > 0) {
      if (tid < 64) {
        const unsigned int tgt = (unsigned int)t;
        for (;;) {
          unsigned int fa, fb;
          asm volatile("global_load_dword %0, %2, off sc1\n\t"
                       "global_load_dword %1, %3, off sc1\n\t"
                       "s_waitcnt vmcnt(0)"
                       : "=&v"(fa), "=&v"(fb)
                       : "v"(gflags + tid), "v"(gflags + 64 + tid));
          if (!__ballot(fa < tgt || fb < tgt)) break;
          __builtin_amdgcn_s_sleep(1);
        }
      }
      __syncthreads();
    }

    // h-part: K = 1024. A fragments via device-scope (sc1) loads that bypass
    // L1/L2 and hit the coherent L3 where writers deposited h. Software
    // pipelined: 4 chunks of 8x dwordx4, prefetch depth 1, partial vmcnt waits.
    {
      const __bf16* hbL = hb + l * 8;
      u32x4 A0[8], A1[8];
      #pragma unroll
      for (int i = 0; i < 8; ++i) A0[i] = ldg_dev16(hbL + i * 512);
      #pragma unroll
      for (int i = 0; i < 8; ++i) A1[i] = ldg_dev16(hbL + (8 + i) * 512);

      CLAIMW("8", A0);                 // A0 (kk 0..7) ready; A1 in flight
      #pragma unroll
      for (int i = 0; i < 8; ++i) {
        bf16x8 b0 = *(const bf16x8*)(whh_lds + i * 512 + l * 8);
        bf16x8 b1 = *(const bf16x8*)(whh_lds + KK_H * 512 + i * 512 + l * 8);
        acc0 = __builtin_amdgcn_mfma_f32_16x16x32_bf16(asbf(A0[i]), b0, acc0, 0, 0, 0);
        acc1 = __builtin_amdgcn_mfma_f32_16x16x32_bf16(asbf(A0[i]), b1, acc1, 0, 0, 0);
      }
      #pragma unroll
      for (int i = 0; i < 8; ++i) A0[i] = ldg_dev16(hbL + (16 + i) * 512);

      CLAIMW("8", A1);                 // A1 (kk 8..15) ready; new A0 in flight
      #pragma unroll
      for (int i = 0; i < 8; ++i) {
        int kk = 8 + i;
        bf16x8 b0 = *(const bf16x8*)(whh_lds + kk * 512 + l * 8);
        bf16x8 b1 = *(const bf16x8*)(whh_lds + KK_H * 512 + kk * 512 + l * 8);
        acc0 = __builtin_amdgcn_mfma_f32_16x16x32_bf16(asbf(A1[i]), b0, acc0, 0, 0, 0);
        acc1 = __builtin_amdgcn_mfma_f32_16x16x32_bf16(asbf(A1[i]), b1, acc1, 0, 0, 0);
      }
      #pragma unroll
      for (int i = 0; i < 8; ++i) A1[i] = ldg_dev16(hbL + (24 + i) * 512);

      CLAIMW("8", A0);                 // A0 (kk 16..23) ready; A1 in flight
      #pragma unroll
      for (int i = 0; i < 8; ++i) {
        int kk = 16 + i;
        bf16x8 b0 = *(const bf16x8*)(whh_lds + kk * 512 + l * 8);
        bf16x8 b1 = *(const bf16x8*)(whh_lds + KK_H * 512 + kk * 512 + l * 8);
        acc0 = __builtin_amdgcn_mfma_f32_16x16x32_bf16(asbf(A0[i]), b0, acc0, 0, 0, 0);
        acc1 = __builtin_amdgcn_mfma_f32_16x16x32_bf16(asbf(A0[i]), b1, acc1, 0, 0, 0);
      }

      CLAIMW("0", A1);                 // A1 (kk 24..31) ready; all loads drained
      #pragma unroll
      for (int i = 0; i < 8; ++i) {
        int kk = 24 + i;
        bf16x8 b0 = *(const bf16x8*)(whh_lds + kk * 512 + l * 8);
        bf16x8 b1 = *(const bf16x8*)(whh_lds + KK_H * 512 + kk * 512 + l * 8);
        acc0 = __builtin_amdgcn_mfma_f32_16x16x32_bf16(asbf(A1[i]), b0, acc0, 0, 0, 0);
        acc1 = __builtin_amdgcn_mfma_f32_16x16x32_bf16(asbf(A1[i]), b1, acc1, 0, 0, 0);
      }
    }

    // stage accumulators (C-layout: col=lane&15, row=(lane>>4)*4+r) to LDS
    {
      int q = l >> 4, n = l & 15;
      float bi0 = bias_lds[n], bi1 = bias_lds[16 + n];
      #pragma unroll
      for (int rr = 0; rr < 4; ++rr) {
        int m = w * 16 + q * 4 + rr;
        gstage[m * 36 + n]      = acc0[rr] + bi0;
        gstage[m * 36 + 16 + n] = acc1[rr] + bi1;
      }
    }
    __syncthreads();

    // gate phase: thread = (m = tid>>2, jq = tid&3) handles j = 2jq, 2jq+1
    // -> one aligned dword device-scope store (write-through to L3)
    {
      __bf16* hw = hbuf + (p * 2 + wb) * HBUF_SLAB;
      int m = tid >> 2, jq = tid & 3;
      int jb = 2 * jq;
      float h2[2];
      #pragma unroll
      for (int s = 0; s < 2; ++s) {
        int j = jb + s;
        float gi = gstage[m * 36 + j];
        float gf = gstage[m * 36 + 8 + j];
        float gg = gstage[m * 36 + 16 + j];
        float go = gstage[m * 36 + 24 + j];
        float i_ = sigmoid_f(gi);
        float f_ = sigmoid_f(gf);
        float g_ = tanh_f(gg);
        float o_ = sigmoid_f(go);
        float c  = f_ * c_lds[m * 8 + j] + i_ * g_;
        c_lds[m * 8 + j] = c;
        h2[s] = o_ * tanh_f(c);
      }
      union { __bf16 h[2]; unsigned int u; } pk;
      pk.h[0] = (__bf16)h2[0];
      pk.h[1] = (__bf16)h2[1];
      int k = j0 + jb;
      int mt = m >> 4, nn = m & 15, kk2 = k >> 5, q2 = (k >> 3) & 3;
      int off = ((mt * 32 + kk2) * 64 + q2 * 16 + nn) * 8 + jb;
      stg_dev4(hw + off, pk.u);
      if (t == SS - 1) {
        hlast[(p * MG + m) * HH + k]     = h2[0];
        hlast[(p * MG + m) * HH + k + 1] = h2[1];
      }
    }

    // ---- signal: drain write-through stores to L3, then release own flag.
    // No threadfence (no L2 writeback/invalidate) anywhere.
    asm volatile("s_waitcnt vmcnt(0)" ::: "memory");
    __syncthreads();
    if (t < SS - 1 && tid == 0) {
      stg_dev4(gflags + bIG, (unsigned int)(t + 1));
    }
  }
}

__global__ void fc_kernel(const float* __restrict__ hlast, const float* __restrict__ W_fc,
                          const float* __restrict__ b_fc, float* __restrict__ out) {
  int b = blockIdx.x;            // 128
  int t = threadIdx.x;           // 256
  int o = t >> 2, part = t & 3;
  const float* hr = hlast + b * HH;
  const float* wr = W_fc + o * HH;
  float s = 0.f;
  #pragma unroll 4
  for (int k0 = part * 4; k0 < HH; k0 += 16) {
    float4 hv = *(const float4*)(hr + k0);
    float4 wv = *(const float4*)(wr + k0);
    s += hv.x * wv.x + hv.y * wv.y + hv.z * wv.z + hv.w * wv.w;
  }
  s += __shfl_xor(s, 1);
  s += __shfl_xor(s, 2);
  if (part == 0) out[b * OO + o] = s + b_fc[o];
}

extern "C" void kernel_launch(void* const* d_in, const int* in_sizes, int n_in,
                              void* d_out, int out_size, void* d_ws, size_t ws_size,
                              hipStream_t stream) {
  const float* x    = (const float*)d_in[0];
  const float* mask = (const float*)d_in[1];
  const float* ti   = (const float*)d_in[2];
  const float* W_ih = (const float*)d_in[3];
  const float* W_hh = (const float*)d_in[4];
  const float* b_ih = (const float*)d_in[5];
  const float* b_hh = (const float*)d_in[6];
  const float* W_fc = (const float*)d_in[7];
  const float* b_fc = (const float*)d_in[8];
  float* out = (float*)d_out;

  char* ws = (char*)d_ws;
  unsigned int* flags = (unsigned int*)ws;
  __bf16* hbuf  = (__bf16*)(ws + WS_HBUF);
  float*  hlast = (float*)(ws + WS_HLAST);
  __bf16* xtp   = (__bf16*)(ws + WS_XTP);

  // zero flags + h double-buffers (ws is poisoned 0xAA before each launch)
  hipMemsetAsync(ws, 0, WS_HLAST, stream);

  prepack_kernel<<<(1024 * XTP_SLAB) / 256, 256, 0, stream>>>(x, mask, ti, xtp);
  lstm_scan<<<NGROUP * GBLK, 256, 0, stream>>>(W_ih, W_hh, b_ih, b_hh, xtp, hbuf, hlast, flags);
  fc_kernel<<<BB, 256, 0, stream>>>(hlast, W_fc, b_fc, out);
}